// Round 19
// baseline (133.296 us; speedup 1.0000x reference)
//
#include <hip/hip_runtime.h>
#include <hip/hip_cooperative_groups.h>
#include <math.h>

#define NN 32
#define CC 512
#define PP 1024   // H*W
#define KK 64
static constexpr float EPS = 1e-12f;

namespace cg = cooperative_groups;

typedef __attribute__((ext_vector_type(8))) short bf16x8;
typedef __attribute__((ext_vector_type(4))) float f32x4;
typedef __attribute__((ext_vector_type(4))) unsigned int u32x4;
union FragU { u32x4 u; bf16x8 h; };

// pack two fp32 into one u32 of 2 bf16 (RNE)
__device__ __forceinline__ unsigned int bfpair(float lo, float hi) {
    unsigned int ul = __builtin_bit_cast(unsigned int, lo);
    unsigned int uh = __builtin_bit_cast(unsigned int, hi);
    ul = ul + 0x7FFFu + ((ul >> 16) & 1u);
    uh = uh + 0x7FFFu + ((uh >> 16) & 1u);
    return (ul >> 16) | (uh & 0xFFFF0000u);
}

// ================= ONE cooperative kernel: logits -> (sync) -> vlad -> (sync) -> scale =================
// grid: 256 blocks (1 block/CU at 105KB LDS -> all co-resident). 512 threads = 8 waves.
__global__ void __launch_bounds__(512, 2) k_fused(
        const float* __restrict__ x, const float* __restrict__ w,
        const float* __restrict__ bias, unsigned int* __restrict__ sab,
        float* __restrict__ Spart, float* __restrict__ ssqpart,
        float* __restrict__ out) {
    cg::grid_group grid = cg::this_grid();
    int b = blockIdx.x;
    int tid = threadIdx.x;
    int lane = tid & 63;
    int wv = __builtin_amdgcn_readfirstlane(tid >> 6);   // 0..7
    int l15 = lane & 15, l4 = lane >> 4;

    __shared__ unsigned int smem_u[26240];   // 104960 B

    // ---------------- PHASE 1: pixnorm + logits(MFMA) + softmax -> sab, Spart ----------------
    {
        int n = b >> 3;
        int p0 = (b & 7) << 7;           // 128-px tile base
        int rp = tid >> 4;               // staging cpair row 0..31
        int px8 = (tid & 15) << 3;       // staging px octet

        unsigned int* XP  = smem_u;              // 2 x [128][33] u32
        unsigned int* WBF = smem_u + 8448;       // [64][260] u32
        float* RED  = (float*)(smem_u + 25088);  // [8][128]
        float* REDI = (float*)(smem_u + 26112);  // [128]

        // stage whole W (fp32 -> bf16 pairs) into LDS once
        {
            int k = tid >> 3, cb = (tid & 7) << 5;
            const float* wsrc = w + (k << 9) + (cb << 1);
#pragma unroll
            for (int i = 0; i < 8; ++i) {
                float4 f0 = *(const float4*)&wsrc[(i << 3)];
                float4 f1 = *(const float4*)&wsrc[(i << 3) + 4];
                u32x4 v;
                v[0] = bfpair(f0.x, f0.y); v[1] = bfpair(f0.z, f0.w);
                v[2] = bfpair(f1.x, f1.y); v[3] = bfpair(f1.z, f1.w);
                *(u32x4*)&WBF[k * 260 + cb + (i << 2)] = v;
            }
        }

        const float* xb = x + (size_t)n * CC * PP + p0;

        f32x4 c0v = {0.f, 0.f, 0.f, 0.f};
        f32x4 c1v = {0.f, 0.f, 0.f, 0.f};
        f32x4 c2v = {0.f, 0.f, 0.f, 0.f};
        f32x4 c3v = {0.f, 0.f, 0.f, 0.f};
        float ssq[8] = {};
        float4 a0, a1, b0, b1;

#define PFL(i) { const float* xa = xb + (size_t)((i) * 64 + 2 * rp) * PP + px8; \
        a0 = *(const float4*)xa; a1 = *(const float4*)(xa + 4); \
        b0 = *(const float4*)(xa + PP); b1 = *(const float4*)(xa + PP + 4); }

#define MSTEP(H) { \
        FragU bfr; \
        int ob = xo + ((H) << 4); \
        bfr.u[0] = xq[ob]; bfr.u[1] = xq[ob + 1]; \
        bfr.u[2] = xq[ob + 2]; bfr.u[3] = xq[ob + 3]; \
        int oa = l15 * 260 + (i << 5) + ((H) << 4) + (l4 << 2); \
        FragU af; \
        af.u = *(const u32x4*)&WBF[oa]; \
        c0v = __builtin_amdgcn_mfma_f32_16x16x32_bf16(af.h, bfr.h, c0v, 0, 0, 0); \
        af.u = *(const u32x4*)&WBF[oa + 4160]; \
        c1v = __builtin_amdgcn_mfma_f32_16x16x32_bf16(af.h, bfr.h, c1v, 0, 0, 0); \
        af.u = *(const u32x4*)&WBF[oa + 8320]; \
        c2v = __builtin_amdgcn_mfma_f32_16x16x32_bf16(af.h, bfr.h, c2v, 0, 0, 0); \
        af.u = *(const u32x4*)&WBF[oa + 12480]; \
        c3v = __builtin_amdgcn_mfma_f32_16x16x32_bf16(af.h, bfr.h, c3v, 0, 0, 0); \
    }

        PFL(0);
#pragma unroll 1
        for (int i = 0; i < 8; ++i) {
            __syncthreads();
            unsigned int* xp = XP + (i & 1) * 4224;
            float av[8] = {a0.x, a0.y, a0.z, a0.w, a1.x, a1.y, a1.z, a1.w};
            float bv[8] = {b0.x, b0.y, b0.z, b0.w, b1.x, b1.y, b1.z, b1.w};
#pragma unroll
            for (int j = 0; j < 8; ++j) {
                xp[(px8 + j) * 33 + rp] = bfpair(av[j], bv[j]);
                ssq[j] = fmaf(av[j], av[j], fmaf(bv[j], bv[j], ssq[j]));
            }
            __syncthreads();
            if (i < 7) { PFL(i + 1); }
            const unsigned int* xq = XP + (i & 1) * 4224;
            int xo = (wv * 16 + l15) * 33 + (l4 << 2);
            MSTEP(0);
            MSTEP(1);
        }
#undef PFL
#undef MSTEP

#pragma unroll
        for (int j = 0; j < 8; ++j) {
            ssq[j] += __shfl_xor(ssq[j], 16);
            ssq[j] += __shfl_xor(ssq[j], 32);
        }
        if (l4 == 0) {
#pragma unroll
            for (int j = 0; j < 8; ++j) RED[(wv << 7) + px8 + j] = ssq[j];
        }
        __syncthreads();
        if (tid < 128) {
            float s = 0.f;
#pragma unroll
            for (int w8 = 0; w8 < 8; ++w8) s += RED[(w8 << 7) + tid];
            REDI[tid] = 1.0f / fmaxf(sqrtf(s), EPS);
        }
        __syncthreads();

        float inv = REDI[(wv << 4) + l15];
        float lg[16];
#pragma unroll
        for (int r = 0; r < 4; ++r) {
            lg[r]      = c0v[r];
            lg[4 + r]  = c1v[r];
            lg[8 + r]  = c2v[r];
            lg[12 + r] = c3v[r];
        }
        float m = -1e30f;
#pragma unroll
        for (int kk = 0; kk < 16; ++kk) {
            int k = ((kk >> 2) << 4) + (l4 << 2) + (kk & 3);
            lg[kk] = fmaf(lg[kk], inv, bias[k]);
            m = fmaxf(m, lg[kk]);
        }
        m = fmaxf(m, __shfl_xor(m, 16));
        m = fmaxf(m, __shfl_xor(m, 32));
        float sm = 0.f;
#pragma unroll
        for (int kk = 0; kk < 16; ++kk) {
            lg[kk] = __expf(lg[kk] - m);
            sm += lg[kk];
        }
        sm += __shfl_xor(sm, 16);
        sm += __shfl_xor(sm, 32);
        float si = 1.0f / sm;

        int pcol = p0 + (wv << 4) + l15;
#pragma unroll
        for (int kk = 0; kk < 16; ++kk) {
            int k = ((kk >> 2) << 4) + (l4 << 2) + (kk & 3);
            float v = lg[kk] * si;
            float vs = v;
            vs += __shfl_xor(vs, 1);
            vs += __shfl_xor(vs, 2);
            vs += __shfl_xor(vs, 4);
            vs += __shfl_xor(vs, 8);
            float vi = v * inv;
            float vh = __shfl_xor(vi, 1);
            if ((l15 & 1) == 0)
                sab[(((size_t)(n * KK + k) << 10) + pcol) >> 1] = bfpair(vi, vh);
            if (l15 == 0) RED[(wv << 6) + k] = vs;
        }
        __syncthreads();
        if (tid < 64) {
            float s = 0.f;
#pragma unroll
            for (int w8 = 0; w8 < 8; ++w8) s += RED[(w8 << 6) + tid];
            Spart[(((b & 7) * NN) + n) * KK + tid] = s;
        }
    }

    grid.sync();

    // ---------------- PHASE 2: vlad MFMA, result stays in registers; ssqpart out ----------------
    int nb = b >> 3;
    int ct = b & 7;
    int c0 = ct << 6;
    int kt = wv & 3;
    int ctb = (wv >> 2) << 1;      // 0 or 2
    float vout0[4], vout1[4];
    {
        unsigned int* SAB = smem_u;             // [2][64][33]
        unsigned int* XT  = smem_u + 4224;      // [2][64][33]
        float* R2 = (float*)(smem_u + 8448);    // [8][16]

        int tr = tid >> 3;
        int tc = tid & 7;

        const unsigned int* sap = sab + ((size_t)(nb * KK + tr) << 9) + (tc << 2);
        const float* xbp = x + ((size_t)(nb * CC + c0 + tr) << 10) + (tc << 3);

        f32x4 acc0 = {0.f, 0.f, 0.f, 0.f};
        f32x4 acc1 = {0.f, 0.f, 0.f, 0.f};

        u32x4 sregA, sregB;
        float4 xrA0, xrA1, xrB0, xrB1;

#define LOADA(i) { sregA = *(const u32x4*)(sap + (i) * 32); \
        xrA0 = *(const float4*)(xbp + (i) * 64); \
        xrA1 = *(const float4*)(xbp + (i) * 64 + 4); }
#define LOADB(i) { sregB = *(const u32x4*)(sap + (i) * 32); \
        xrB0 = *(const float4*)(xbp + (i) * 64); \
        xrB1 = *(const float4*)(xbp + (i) * 64 + 4); }

#define BODY(SREG, XR0, XR1, i, LOADNEXT) { \
        __syncthreads(); \
        int bo = ((i) & 1) * 2112; \
        *(u32x4*)(SAB + bo + tr * 33 + (tc << 2)) = SREG; \
        u32x4 xw; \
        xw[0] = bfpair(XR0.x, XR0.y); \
        xw[1] = bfpair(XR0.z, XR0.w); \
        xw[2] = bfpair(XR1.x, XR1.y); \
        xw[3] = bfpair(XR1.z, XR1.w); \
        *(u32x4*)(XT + bo + tr * 33 + (tc << 2)) = xw; \
        __syncthreads(); \
        LOADNEXT; \
        const unsigned int* sa_l = SAB + bo + (kt * 16 + l15) * 33 + (l4 << 2); \
        const unsigned int* xb0  = XT + bo + (ctb * 16 + l15) * 33 + (l4 << 2); \
        _Pragma("unroll") \
        for (int s = 0; s < 2; ++s) { \
            FragU af, bf0, bf1; \
            af.u  = *(const u32x4*)(sa_l + s * 16); \
            bf0.u = *(const u32x4*)(xb0 + s * 16); \
            bf1.u = *(const u32x4*)(xb0 + 16 * 33 + s * 16); \
            acc0 = __builtin_amdgcn_mfma_f32_16x16x32_bf16(af.h, bf0.h, acc0, 0, 0, 0); \
            acc1 = __builtin_amdgcn_mfma_f32_16x16x32_bf16(af.h, bf1.h, acc1, 0, 0, 0); \
        } \
    }

        LOADA(0); LOADB(1);
#pragma unroll 1
        for (int i = 0; i < 16; i += 2) {
            if (i < 14) { BODY(sregA, xrA0, xrA1, i, LOADA(i + 2)); }
            else        { BODY(sregA, xrA0, xrA1, i, ); }
            if (i < 13) { BODY(sregB, xrB0, xrB1, i + 1, LOADB(i + 3)); }
            else        { BODY(sregB, xrB0, xrB1, i + 1, ); }
        }
#undef LOADA
#undef LOADB
#undef BODY

        // epilogue: v = acc - S*cent kept in registers; row-sumsq partials -> ssqpart
#pragma unroll
        for (int r = 0; r < 4; ++r) {
            int k = kt * 16 + (l4 << 2) + r;
            float S = 0.f;
#pragma unroll
            for (int pt = 0; pt < 8; ++pt) S += Spart[(pt * NN + nb) * KK + k];
            int cg = c0 + ctb * 16 + l15;
            const float* cp = (const float*)out;   // placeholder avoided; cent passed via w? no:
            (void)cp;
            // cent pointer is passed through 'bias'? No — see launch: cent piggybacks via Spart? 
            // (cent is a real kernel arg below)
            vout0[r] = acc0[r];
            vout1[r] = acc1[r];
        }
        // NOTE: S*cent subtraction moved below (needs cent arg) — done in the block after
        // we re-load S once per r to keep register pressure flat.
        __syncthreads();
        // compute with cent now
        {
            const float* cent = (const float*)Spart + 8 * NN * KK;   // cent copied right after Spart
#pragma unroll
            for (int r = 0; r < 4; ++r) {
                int k = kt * 16 + (l4 << 2) + r;
                float S = 0.f;
#pragma unroll
                for (int pt = 0; pt < 8; ++pt) S += Spart[(pt * NN + nb) * KK + k];
                int cg = c0 + ctb * 16 + l15;
                const float* cp = cent + (size_t)k * CC + cg;
                vout0[r] = fmaf(-S, cp[0],  vout0[r]);
                vout1[r] = fmaf(-S, cp[16], vout1[r]);
                float sq = fmaf(vout0[r], vout0[r], vout1[r] * vout1[r]);
                sq += __shfl_xor(sq, 1);
                sq += __shfl_xor(sq, 2);
                sq += __shfl_xor(sq, 4);
                sq += __shfl_xor(sq, 8);
                if (l15 == 0) R2[(wv << 4) + (l4 << 2) + r] = sq;
            }
        }
        __syncthreads();
        if (tid < 64) {
            int kt2 = tid >> 4, kl = tid & 15;
            ssqpart[(ct * NN + nb) * KK + tid] =
                R2[(kt2 << 4) + kl] + R2[((kt2 + 4) << 4) + kl];
        }
    }

    grid.sync();

    // ---------------- PHASE 3: rinv/tinv from ssqpart, scale registers -> out ----------------
    {
        float* RINV = (float*)smem_u;        // [64]
        float* TINV = RINV + 64;             // [1]
        if (tid < 64) {
            float s = 0.f;
#pragma unroll
            for (int c8 = 0; c8 < 8; ++c8) s += ssqpart[(c8 * NN + nb) * KK + tid];
            float iv = 1.0f / fmaxf(sqrtf(s), EPS);
            RINV[tid] = iv;
            float rq = s * iv * iv;
#pragma unroll
            for (int off = 32; off > 0; off >>= 1) rq += __shfl_xor(rq, off);
            if (tid == 0) TINV[0] = 1.0f / fmaxf(sqrtf(rq), EPS);
        }
        __syncthreads();
        float tinv = TINV[0];
#pragma unroll
        for (int r = 0; r < 4; ++r) {
            int k = kt * 16 + (l4 << 2) + r;
            float sc = RINV[k] * tinv;
            int cg = c0 + ctb * 16 + l15;
            float* op = out + ((size_t)nb * KK + k) * CC + cg;
            op[0]  = vout0[r] * sc;
            op[16] = vout1[r] * sc;
        }
    }
}

// copy cent into workspace right after Spart (so phase 2 can address it off one base)
__global__ void k_centcopy(const float* __restrict__ cent, float* __restrict__ dst) {
    int i = blockIdx.x * 256 + threadIdx.x;   // over K*C = 32768
    dst[i] = cent[i];
}

extern "C" void kernel_launch(void* const* d_in, const int* in_sizes, int n_in,
                              void* d_out, int out_size, void* d_ws, size_t ws_size,
                              hipStream_t stream) {
    const float* x    = (const float*)d_in[0];
    const float* w    = (const float*)d_in[1];
    const float* bias = (const float*)d_in[2];
    const float* cent = (const float*)d_in[3];
    float* ws = (float*)d_ws;

    float* Spart   = ws;                          // 16384  (cent copy lives right after)
    float* centws  = Spart + 8 * NN * KK;         // 32768
    float* ssqpart = centws + KK * CC;            // 16384
    unsigned int* sab = (unsigned int*)(ssqpart + 8 * NN * KK);   // 1048576 u32

    float* out = (float*)d_out;

    k_centcopy<<<dim3(128), dim3(256), 0, stream>>>(cent, centws);

    void* args[] = {(void*)&x, (void*)&w, (void*)&bias, (void*)&sab,
                    (void*)&Spart, (void*)&ssqpart, (void*)&out};
    hipLaunchCooperativeKernel((void*)k_fused, dim3(256), dim3(512), args, 0, stream);
}

// Round 20
// 46.481 us; speedup vs baseline: 2.8678x; 2.8678x over previous
//
#include <hip/hip_runtime.h>
#include <math.h>

#define NN 32
#define CC 512
#define PP 1024   // H*W
#define KK 64
static constexpr float EPS = 1e-12f;

typedef __attribute__((ext_vector_type(8))) short bf16x8;
typedef __attribute__((ext_vector_type(4))) float f32x4;
typedef __attribute__((ext_vector_type(4))) unsigned int u32x4;
union FragU { u32x4 u; bf16x8 h; };

// pack two fp32 into one u32 of 2 bf16 (RNE)
__device__ __forceinline__ unsigned int bfpair(float lo, float hi) {
    unsigned int ul = __builtin_bit_cast(unsigned int, lo);
    unsigned int uh = __builtin_bit_cast(unsigned int, hi);
    ul = ul + 0x7FFFu + ((ul >> 16) & 1u);
    uh = uh + 0x7FFFu + ((uh >> 16) & 1u);
    return (ul >> 16) | (uh & 0xFFFF0000u);
}

// ---------------- fused pixnorm + logits(MFMA) + softmax -> sab=(sa*iv) bf16, Spart ----------------
// grid: 256 blocks = n(32) x 128-px tile(8). 512 threads = 8 waves. (R17 verbatim)
__global__ void __launch_bounds__(512, 2) k_logits(
        const float* __restrict__ x, const float* __restrict__ w,
        const float* __restrict__ bias, unsigned int* __restrict__ sab,
        float* __restrict__ Spart) {
    int b = blockIdx.x;
    int n = b >> 3;
    int p0 = (b & 7) << 7;           // 128-px tile base
    int tid = threadIdx.x;
    int lane = tid & 63;
    int wv = __builtin_amdgcn_readfirstlane(tid >> 6);   // 0..7 = px tile
    int l15 = lane & 15, l4 = lane >> 4;
    int rp = tid >> 4;               // staging cpair row 0..31
    int px8 = (tid & 15) << 3;       // staging px octet

    __shared__ unsigned int smem_u[26240];   // 104960 B
    unsigned int* XP  = smem_u;              // 2 x [128][33] u32
    unsigned int* WBF = smem_u + 8448;       // [64][260] u32
    float* RED  = (float*)(smem_u + 25088);  // [8][128]
    float* REDI = (float*)(smem_u + 26112);  // [128]

    // ---- stage whole W (fp32 -> bf16 pairs) into LDS once ----
    {
        int k = tid >> 3, cb = (tid & 7) << 5;
        const float* wsrc = w + (k << 9) + (cb << 1);
#pragma unroll
        for (int i = 0; i < 8; ++i) {
            float4 f0 = *(const float4*)&wsrc[(i << 3)];
            float4 f1 = *(const float4*)&wsrc[(i << 3) + 4];
            u32x4 v;
            v[0] = bfpair(f0.x, f0.y); v[1] = bfpair(f0.z, f0.w);
            v[2] = bfpair(f1.x, f1.y); v[3] = bfpair(f1.z, f1.w);
            *(u32x4*)&WBF[k * 260 + cb + (i << 2)] = v;
        }
    }

    const float* xb = x + (size_t)n * CC * PP + p0;

    f32x4 c0v = {0.f, 0.f, 0.f, 0.f};
    f32x4 c1v = {0.f, 0.f, 0.f, 0.f};
    f32x4 c2v = {0.f, 0.f, 0.f, 0.f};
    f32x4 c3v = {0.f, 0.f, 0.f, 0.f};
    float ssq[8] = {};
    float4 a0, a1, b0, b1;

#define PFL(i) { const float* xa = xb + (size_t)((i) * 64 + 2 * rp) * PP + px8; \
        a0 = *(const float4*)xa; a1 = *(const float4*)(xa + 4); \
        b0 = *(const float4*)(xa + PP); b1 = *(const float4*)(xa + PP + 4); }

#define MSTEP(H) { \
        FragU bfr; \
        int ob = xo + ((H) << 4); \
        bfr.u[0] = xq[ob]; bfr.u[1] = xq[ob + 1]; \
        bfr.u[2] = xq[ob + 2]; bfr.u[3] = xq[ob + 3]; \
        int oa = l15 * 260 + (i << 5) + ((H) << 4) + (l4 << 2); \
        FragU af; \
        af.u = *(const u32x4*)&WBF[oa]; \
        c0v = __builtin_amdgcn_mfma_f32_16x16x32_bf16(af.h, bfr.h, c0v, 0, 0, 0); \
        af.u = *(const u32x4*)&WBF[oa + 4160]; \
        c1v = __builtin_amdgcn_mfma_f32_16x16x32_bf16(af.h, bfr.h, c1v, 0, 0, 0); \
        af.u = *(const u32x4*)&WBF[oa + 8320]; \
        c2v = __builtin_amdgcn_mfma_f32_16x16x32_bf16(af.h, bfr.h, c2v, 0, 0, 0); \
        af.u = *(const u32x4*)&WBF[oa + 12480]; \
        c3v = __builtin_amdgcn_mfma_f32_16x16x32_bf16(af.h, bfr.h, c3v, 0, 0, 0); \
    }

    PFL(0);
#pragma unroll 1
    for (int i = 0; i < 8; ++i) {
        __syncthreads();
        unsigned int* xp = XP + (i & 1) * 4224;
        float av[8] = {a0.x, a0.y, a0.z, a0.w, a1.x, a1.y, a1.z, a1.w};
        float bv[8] = {b0.x, b0.y, b0.z, b0.w, b1.x, b1.y, b1.z, b1.w};
#pragma unroll
        for (int j = 0; j < 8; ++j) {
            xp[(px8 + j) * 33 + rp] = bfpair(av[j], bv[j]);
            ssq[j] = fmaf(av[j], av[j], fmaf(bv[j], bv[j], ssq[j]));
        }
        __syncthreads();
        if (i < 7) { PFL(i + 1); }
        const unsigned int* xq = XP + (i & 1) * 4224;
        int xo = (wv * 16 + l15) * 33 + (l4 << 2);
        MSTEP(0);
        MSTEP(1);
    }
#undef PFL
#undef MSTEP

#pragma unroll
    for (int j = 0; j < 8; ++j) {
        ssq[j] += __shfl_xor(ssq[j], 16);
        ssq[j] += __shfl_xor(ssq[j], 32);
    }
    if (l4 == 0) {
#pragma unroll
        for (int j = 0; j < 8; ++j) RED[(wv << 7) + px8 + j] = ssq[j];
    }
    __syncthreads();
    if (tid < 128) {
        float s = 0.f;
#pragma unroll
        for (int w8 = 0; w8 < 8; ++w8) s += RED[(w8 << 7) + tid];
        REDI[tid] = 1.0f / fmaxf(sqrtf(s), EPS);
    }
    __syncthreads();

    float inv = REDI[(wv << 4) + l15];
    float lg[16];
#pragma unroll
    for (int r = 0; r < 4; ++r) {
        lg[r]      = c0v[r];
        lg[4 + r]  = c1v[r];
        lg[8 + r]  = c2v[r];
        lg[12 + r] = c3v[r];
    }
    float m = -1e30f;
#pragma unroll
    for (int kk = 0; kk < 16; ++kk) {
        int k = ((kk >> 2) << 4) + (l4 << 2) + (kk & 3);
        lg[kk] = fmaf(lg[kk], inv, bias[k]);
        m = fmaxf(m, lg[kk]);
    }
    m = fmaxf(m, __shfl_xor(m, 16));
    m = fmaxf(m, __shfl_xor(m, 32));
    float sm = 0.f;
#pragma unroll
    for (int kk = 0; kk < 16; ++kk) {
        lg[kk] = __expf(lg[kk] - m);
        sm += lg[kk];
    }
    sm += __shfl_xor(sm, 16);
    sm += __shfl_xor(sm, 32);
    float si = 1.0f / sm;

    int pcol = p0 + (wv << 4) + l15;
#pragma unroll
    for (int kk = 0; kk < 16; ++kk) {
        int k = ((kk >> 2) << 4) + (l4 << 2) + (kk & 3);
        float v = lg[kk] * si;
        float vs = v;
        vs += __shfl_xor(vs, 1);
        vs += __shfl_xor(vs, 2);
        vs += __shfl_xor(vs, 4);
        vs += __shfl_xor(vs, 8);
        float vi = v * inv;
        float vh = __shfl_xor(vi, 1);
        if ((l15 & 1) == 0)
            sab[(((size_t)(n * KK + k) << 10) + pcol) >> 1] = bfpair(vi, vh);
        if (l15 == 0) RED[(wv << 6) + k] = vs;
    }
    __syncthreads();
    if (tid < 64) {
        float s = 0.f;
#pragma unroll
        for (int w8 = 0; w8 < 8; ++w8) s += RED[(w8 << 6) + tid];
        Spart[(((b & 7) * NN) + n) * KK + tid] = s;
    }
}

// ---------------- vlad[n][k][c] (MFMA) — wave-contiguous staging, 256-px chunks ----------------
// grid: 256 blocks; nb = b&31, ct = b>>5 (the 8 sab-sharing c-tiles land on one XCD).
// 512 threads = 8 waves. 4 chunks of 256 px, double-buffered.
// Staging: wave w loads rows w*8+j whole: sab uint2/lane (512B/instr contiguous),
// x float4/lane (1KB/instr contiguous) -> single-segment coalesced loads.
// LDS rows padded to 129 u32 (mod-32 bank stride 1, same as proven pad-33).
__global__ void __launch_bounds__(512) k_vlad(
        const float* __restrict__ x, const unsigned int* __restrict__ sab,
        const float* __restrict__ Spart, const float* __restrict__ cent,
        float* __restrict__ vlad, float* __restrict__ ssqpart) {
    int b = blockIdx.x;
    int nb = b & 31;
    int ct = b >> 5;
    int c0 = ct << 6;
    int tid = threadIdx.x;
    int lane = tid & 63;
    int wv = __builtin_amdgcn_readfirstlane(tid >> 6);   // 0..7
    int l15 = lane & 15, l4 = lane >> 4;
    int kt = wv & 3;
    int ctb = (wv >> 2) << 1;      // 0 or 2

    // buffer = SAB[64][129] + XT[64][129]; two buffers + R2
    __shared__ unsigned int smem_u[33152];   // 132608 B (2*16512 + 128)
    float* R2 = (float*)(smem_u + 33024);    // [8][16]

    const unsigned int* sabp = sab + ((size_t)(nb * KK) << 9);
    const float* xp = x + ((size_t)(nb * CC + c0) << 10);

    f32x4 acc0 = {0.f, 0.f, 0.f, 0.f};
    f32x4 acc1 = {0.f, 0.f, 0.f, 0.f};

    uint2 sA[8], sB[8];
    float4 xA[8], xB[8];

#define LOADV(XS, SS, i) { \
        _Pragma("unroll") \
        for (int j = 0; j < 8; ++j) { \
            int r = (wv << 3) + j; \
            SS[j] = *(const uint2*)(sabp + ((size_t)r << 9) + ((i) << 7) + (lane << 1)); \
            XS[j] = *(const float4*)(xp + ((size_t)r << 10) + ((i) << 8) + (lane << 2)); \
        } }

#define BODYV(XS, SS, i, LOADNEXT) { \
        __syncthreads(); \
        int bo = ((i) & 1) * 16512; \
        _Pragma("unroll") \
        for (int j = 0; j < 8; ++j) { \
            int r = (wv << 3) + j; \
            *(uint2*)(smem_u + bo + r * 129 + (lane << 1)) = SS[j]; \
            uint2 xw; \
            xw.x = bfpair(XS[j].x, XS[j].y); \
            xw.y = bfpair(XS[j].z, XS[j].w); \
            *(uint2*)(smem_u + bo + 8256 + r * 129 + (lane << 1)) = xw; \
        } \
        __syncthreads(); \
        LOADNEXT; \
        _Pragma("unroll") \
        for (int ks = 0; ks < 8; ++ks) { \
            FragU af, bf0, bf1; \
            af.u  = *(const u32x4*)(smem_u + bo + (kt * 16 + l15) * 129 + (l4 << 2) + (ks << 4)); \
            bf0.u = *(const u32x4*)(smem_u + bo + 8256 + (ctb * 16 + l15) * 129 + (l4 << 2) + (ks << 4)); \
            bf1.u = *(const u32x4*)(smem_u + bo + 8256 + ((ctb + 1) * 16 + l15) * 129 + (l4 << 2) + (ks << 4)); \
            acc0 = __builtin_amdgcn_mfma_f32_16x16x32_bf16(af.h, bf0.h, acc0, 0, 0, 0); \
            acc1 = __builtin_amdgcn_mfma_f32_16x16x32_bf16(af.h, bf1.h, acc1, 0, 0, 0); \
        } }

    LOADV(xA, sA, 0);
    LOADV(xB, sB, 1);
    BODYV(xA, sA, 0, LOADV(xA, sA, 2));
    BODYV(xB, sB, 1, LOADV(xB, sB, 3));
    BODYV(xA, sA, 2, );
    BODYV(xB, sB, 3, );
#undef LOADV
#undef BODYV

    // ---- fused epilogue: vlad = acc - S*cent, row-sumsq partials -> ssqpart ----
#pragma unroll
    for (int r = 0; r < 4; ++r) {
        int k = kt * 16 + (l4 << 2) + r;
        float S = 0.f;
#pragma unroll
        for (int pt = 0; pt < 8; ++pt) S += Spart[(pt * NN + nb) * KK + k];
        int cg = c0 + ctb * 16 + l15;
        const float* cp = cent + (size_t)k * CC + cg;
        float v0 = fmaf(-S, cp[0],  acc0[r]);
        float v1 = fmaf(-S, cp[16], acc1[r]);
        float* vp = vlad + ((size_t)nb * KK + k) * CC + cg;
        vp[0]  = v0;
        vp[16] = v1;
        float sq = fmaf(v0, v0, v1 * v1);
        sq += __shfl_xor(sq, 1);
        sq += __shfl_xor(sq, 2);
        sq += __shfl_xor(sq, 4);
        sq += __shfl_xor(sq, 8);
        if (l15 == 0) R2[(wv << 4) + (l4 << 2) + r] = sq;
    }
    __syncthreads();
    if (tid < 64) {
        int kt2 = tid >> 4, kl = tid & 15;
        ssqpart[(ct * NN + nb) * KK + tid] =
            R2[(kt2 << 4) + kl] + R2[((kt2 + 4) << 4) + kl];
    }
}

// ---------------- final scale: rinv/tinv from ssqpart, out = vlad*rinv*tinv ----------------
__global__ void k_final(const float* __restrict__ vlad, const float* __restrict__ ssqpart,
                        float* __restrict__ out) {
    size_t i4 = (size_t)blockIdx.x * 256 + threadIdx.x;
    int row = (int)(i4 >> 7);
    int n = row >> 6;
    int lane = threadIdx.x & 63;
    float s = 0.f;
#pragma unroll
    for (int ctile = 0; ctile < 8; ++ctile)
        s += ssqpart[(ctile * NN + n) * KK + lane];
    float iv = 1.0f / fmaxf(sqrtf(s), EPS);
    float rq = s * iv * iv;
#pragma unroll
    for (int off = 32; off > 0; off >>= 1) rq += __shfl_xor(rq, off);
    float tinv = 1.0f / fmaxf(sqrtf(rq), EPS);
    float rinv = __shfl(iv, row & 63);
    float4 v = ((const float4*)vlad)[i4];
    float sc = rinv * tinv;
    float4 o{v.x * sc, v.y * sc, v.z * sc, v.w * sc};
    ((float4*)out)[i4] = o;
}

extern "C" void kernel_launch(void* const* d_in, const int* in_sizes, int n_in,
                              void* d_out, int out_size, void* d_ws, size_t ws_size,
                              hipStream_t stream) {
    const float* x    = (const float*)d_in[0];
    const float* w    = (const float*)d_in[1];
    const float* bias = (const float*)d_in[2];
    const float* cent = (const float*)d_in[3];
    float* ws = (float*)d_ws;

    float* vlad    = ws;                              // 1048576
    float* Spart   = vlad + (size_t)NN * KK * CC;     // 16384
    float* ssqpart = Spart + 8 * NN * KK;             // 16384
    unsigned int* sab = (unsigned int*)(ssqpart + 8 * NN * KK);   // 1048576 u32

    float* out = (float*)d_out;

    k_logits<<<dim3(256), dim3(512), 0, stream>>>(x, w, bias, sab, Spart);
    k_vlad<<<dim3(256), dim3(512), 0, stream>>>(x, sab, Spart, cent, vlad, ssqpart);
    k_final<<<dim3(1024), dim3(256), 0, stream>>>(vlad, ssqpart, out);
}

// Round 21
// 45.515 us; speedup vs baseline: 2.9286x; 1.0212x over previous
//
#include <hip/hip_runtime.h>
#include <math.h>

#define NN 32
#define CC 512
#define PP 1024   // H*W
#define KK 64
static constexpr float EPS = 1e-12f;

typedef __attribute__((ext_vector_type(8))) short bf16x8;
typedef __attribute__((ext_vector_type(4))) float f32x4;
typedef __attribute__((ext_vector_type(4))) unsigned int u32x4;
union FragU { u32x4 u; bf16x8 h; };

// pack two fp32 into one u32 of 2 bf16 (RNE)
__device__ __forceinline__ unsigned int bfpair(float lo, float hi) {
    unsigned int ul = __builtin_bit_cast(unsigned int, lo);
    unsigned int uh = __builtin_bit_cast(unsigned int, hi);
    ul = ul + 0x7FFFu + ((ul >> 16) & 1u);
    uh = uh + 0x7FFFu + ((uh >> 16) & 1u);
    return (ul >> 16) | (uh & 0xFFFF0000u);
}

// ---------------- fused pixnorm + logits(MFMA) + softmax -> sab=(sa*iv) bf16, Spart ----------------
// grid: 256 blocks = n(32) x 128-px tile(8). 512 threads = 8 waves. (R20 verbatim)
__global__ void __launch_bounds__(512, 2) k_logits(
        const float* __restrict__ x, const float* __restrict__ w,
        const float* __restrict__ bias, unsigned int* __restrict__ sab,
        float* __restrict__ Spart) {
    int b = blockIdx.x;
    int n = b >> 3;
    int p0 = (b & 7) << 7;           // 128-px tile base
    int tid = threadIdx.x;
    int lane = tid & 63;
    int wv = __builtin_amdgcn_readfirstlane(tid >> 6);   // 0..7 = px tile
    int l15 = lane & 15, l4 = lane >> 4;
    int rp = tid >> 4;               // staging cpair row 0..31
    int px8 = (tid & 15) << 3;       // staging px octet

    __shared__ unsigned int smem_u[26240];   // 104960 B
    unsigned int* XP  = smem_u;              // 2 x [128][33] u32
    unsigned int* WBF = smem_u + 8448;       // [64][260] u32
    float* RED  = (float*)(smem_u + 25088);  // [8][128]
    float* REDI = (float*)(smem_u + 26112);  // [128]

    // ---- stage whole W (fp32 -> bf16 pairs) into LDS once ----
    {
        int k = tid >> 3, cb = (tid & 7) << 5;
        const float* wsrc = w + (k << 9) + (cb << 1);
#pragma unroll
        for (int i = 0; i < 8; ++i) {
            float4 f0 = *(const float4*)&wsrc[(i << 3)];
            float4 f1 = *(const float4*)&wsrc[(i << 3) + 4];
            u32x4 v;
            v[0] = bfpair(f0.x, f0.y); v[1] = bfpair(f0.z, f0.w);
            v[2] = bfpair(f1.x, f1.y); v[3] = bfpair(f1.z, f1.w);
            *(u32x4*)&WBF[k * 260 + cb + (i << 2)] = v;
        }
    }

    const float* xb = x + (size_t)n * CC * PP + p0;

    f32x4 c0v = {0.f, 0.f, 0.f, 0.f};
    f32x4 c1v = {0.f, 0.f, 0.f, 0.f};
    f32x4 c2v = {0.f, 0.f, 0.f, 0.f};
    f32x4 c3v = {0.f, 0.f, 0.f, 0.f};
    float ssq[8] = {};
    float4 a0, a1, b0, b1;

#define PFL(i) { const float* xa = xb + (size_t)((i) * 64 + 2 * rp) * PP + px8; \
        a0 = *(const float4*)xa; a1 = *(const float4*)(xa + 4); \
        b0 = *(const float4*)(xa + PP); b1 = *(const float4*)(xa + PP + 4); }

#define MSTEP(H) { \
        FragU bfr; \
        int ob = xo + ((H) << 4); \
        bfr.u[0] = xq[ob]; bfr.u[1] = xq[ob + 1]; \
        bfr.u[2] = xq[ob + 2]; bfr.u[3] = xq[ob + 3]; \
        int oa = l15 * 260 + (i << 5) + ((H) << 4) + (l4 << 2); \
        FragU af; \
        af.u = *(const u32x4*)&WBF[oa]; \
        c0v = __builtin_amdgcn_mfma_f32_16x16x32_bf16(af.h, bfr.h, c0v, 0, 0, 0); \
        af.u = *(const u32x4*)&WBF[oa + 4160]; \
        c1v = __builtin_amdgcn_mfma_f32_16x16x32_bf16(af.h, bfr.h, c1v, 0, 0, 0); \
        af.u = *(const u32x4*)&WBF[oa + 8320]; \
        c2v = __builtin_amdgcn_mfma_f32_16x16x32_bf16(af.h, bfr.h, c2v, 0, 0, 0); \
        af.u = *(const u32x4*)&WBF[oa + 12480]; \
        c3v = __builtin_amdgcn_mfma_f32_16x16x32_bf16(af.h, bfr.h, c3v, 0, 0, 0); \
    }

    PFL(0);
#pragma unroll 1
    for (int i = 0; i < 8; ++i) {
        __syncthreads();
        unsigned int* xp = XP + (i & 1) * 4224;
        float av[8] = {a0.x, a0.y, a0.z, a0.w, a1.x, a1.y, a1.z, a1.w};
        float bv[8] = {b0.x, b0.y, b0.z, b0.w, b1.x, b1.y, b1.z, b1.w};
#pragma unroll
        for (int j = 0; j < 8; ++j) {
            xp[(px8 + j) * 33 + rp] = bfpair(av[j], bv[j]);
            ssq[j] = fmaf(av[j], av[j], fmaf(bv[j], bv[j], ssq[j]));
        }
        __syncthreads();
        if (i < 7) { PFL(i + 1); }
        const unsigned int* xq = XP + (i & 1) * 4224;
        int xo = (wv * 16 + l15) * 33 + (l4 << 2);
        MSTEP(0);
        MSTEP(1);
    }
#undef PFL
#undef MSTEP

#pragma unroll
    for (int j = 0; j < 8; ++j) {
        ssq[j] += __shfl_xor(ssq[j], 16);
        ssq[j] += __shfl_xor(ssq[j], 32);
    }
    if (l4 == 0) {
#pragma unroll
        for (int j = 0; j < 8; ++j) RED[(wv << 7) + px8 + j] = ssq[j];
    }
    __syncthreads();
    if (tid < 128) {
        float s = 0.f;
#pragma unroll
        for (int w8 = 0; w8 < 8; ++w8) s += RED[(w8 << 7) + tid];
        REDI[tid] = 1.0f / fmaxf(sqrtf(s), EPS);
    }
    __syncthreads();

    float inv = REDI[(wv << 4) + l15];
    float lg[16];
#pragma unroll
    for (int r = 0; r < 4; ++r) {
        lg[r]      = c0v[r];
        lg[4 + r]  = c1v[r];
        lg[8 + r]  = c2v[r];
        lg[12 + r] = c3v[r];
    }
    float m = -1e30f;
#pragma unroll
    for (int kk = 0; kk < 16; ++kk) {
        int k = ((kk >> 2) << 4) + (l4 << 2) + (kk & 3);
        lg[kk] = fmaf(lg[kk], inv, bias[k]);
        m = fmaxf(m, lg[kk]);
    }
    m = fmaxf(m, __shfl_xor(m, 16));
    m = fmaxf(m, __shfl_xor(m, 32));
    float sm = 0.f;
#pragma unroll
    for (int kk = 0; kk < 16; ++kk) {
        lg[kk] = __expf(lg[kk] - m);
        sm += lg[kk];
    }
    sm += __shfl_xor(sm, 16);
    sm += __shfl_xor(sm, 32);
    float si = 1.0f / sm;

    int pcol = p0 + (wv << 4) + l15;
#pragma unroll
    for (int kk = 0; kk < 16; ++kk) {
        int k = ((kk >> 2) << 4) + (l4 << 2) + (kk & 3);
        float v = lg[kk] * si;
        float vs = v;
        vs += __shfl_xor(vs, 1);
        vs += __shfl_xor(vs, 2);
        vs += __shfl_xor(vs, 4);
        vs += __shfl_xor(vs, 8);
        float vi = v * inv;
        float vh = __shfl_xor(vi, 1);
        if ((l15 & 1) == 0)
            sab[(((size_t)(n * KK + k) << 10) + pcol) >> 1] = bfpair(vi, vh);
        if (l15 == 0) RED[(wv << 6) + k] = vs;
    }
    __syncthreads();
    if (tid < 64) {
        float s = 0.f;
#pragma unroll
        for (int w8 = 0; w8 < 8; ++w8) s += RED[(w8 << 6) + tid];
        Spart[(((b & 7) * NN) + n) * KK + tid] = s;
    }
}

// ---------------- vlad[n][k][c] (MFMA) — wave-contiguous x staging; A-frags direct from L2 ----------------
// grid: 256 blocks; nb = b&31, ct = b>>5 (same-nb blocks share an XCD -> sab L2-hot).
// 512 threads = 8 waves. 4 chunks of 256 px, double-buffered XT only (66KB LDS).
// A-fragments (sab) prefetched straight into registers (8 x u32x4 per chunk, 64B-coalesced
// L2 gathers) — no SAB LDS round-trip. Bit-identical to R20.
__global__ void __launch_bounds__(512) k_vlad(
        const float* __restrict__ x, const unsigned int* __restrict__ sab,
        const float* __restrict__ Spart, const float* __restrict__ cent,
        float* __restrict__ vlad, float* __restrict__ ssqpart) {
    int b = blockIdx.x;
    int nb = b & 31;
    int ct = b >> 5;
    int c0 = ct << 6;
    int tid = threadIdx.x;
    int lane = tid & 63;
    int wv = __builtin_amdgcn_readfirstlane(tid >> 6);   // 0..7
    int l15 = lane & 15, l4 = lane >> 4;
    int kt = wv & 3;
    int ctb = (wv >> 2) << 1;      // 0 or 2

    __shared__ unsigned int smem_u[16640];   // 66560 B: 2 x XT[64][129] + R2
    float* R2 = (float*)(smem_u + 16512);    // [8][16]

    const float* xp = x + ((size_t)(nb * CC + c0) << 10);
    // this lane's sab row (A-operand row) base, in u32
    const unsigned int* arow = sab + ((size_t)(nb * KK + kt * 16 + l15) << 9) + (l4 << 2);

    f32x4 acc0 = {0.f, 0.f, 0.f, 0.f};
    f32x4 acc1 = {0.f, 0.f, 0.f, 0.f};

    float4 xA[8], xB[8];
    u32x4 aA[8], aB[8];

#define LOADV(XS, AS, i) { \
        _Pragma("unroll") \
        for (int j = 0; j < 8; ++j) { \
            int r = (wv << 3) + j; \
            XS[j] = *(const float4*)(xp + ((size_t)r << 10) + ((i) << 8) + (lane << 2)); \
            AS[j] = *(const u32x4*)(arow + ((i) << 7) + (j << 4)); \
        } }

#define BODYV(XS, AS, i, LOADNEXT) { \
        __syncthreads(); \
        int bo = ((i) & 1) * 8256; \
        _Pragma("unroll") \
        for (int j = 0; j < 8; ++j) { \
            int r = (wv << 3) + j; \
            uint2 xw; \
            xw.x = bfpair(XS[j].x, XS[j].y); \
            xw.y = bfpair(XS[j].z, XS[j].w); \
            *(uint2*)(smem_u + bo + r * 129 + (lane << 1)) = xw; \
        } \
        __syncthreads(); \
        LOADNEXT; \
        _Pragma("unroll") \
        for (int ks = 0; ks < 8; ++ks) { \
            FragU af, bf0, bf1; \
            af.u  = AS[ks]; \
            bf0.u = *(const u32x4*)(smem_u + bo + (ctb * 16 + l15) * 129 + (l4 << 2) + (ks << 4)); \
            bf1.u = *(const u32x4*)(smem_u + bo + ((ctb + 1) * 16 + l15) * 129 + (l4 << 2) + (ks << 4)); \
            acc0 = __builtin_amdgcn_mfma_f32_16x16x32_bf16(af.h, bf0.h, acc0, 0, 0, 0); \
            acc1 = __builtin_amdgcn_mfma_f32_16x16x32_bf16(af.h, bf1.h, acc1, 0, 0, 0); \
        } }

    LOADV(xA, aA, 0);
    LOADV(xB, aB, 1);
    BODYV(xA, aA, 0, LOADV(xA, aA, 2));
    BODYV(xB, aB, 1, LOADV(xB, aB, 3));
    BODYV(xA, aA, 2, );
    BODYV(xB, aB, 3, );
#undef LOADV
#undef BODYV

    // ---- fused epilogue: vlad = acc - S*cent, row-sumsq partials -> ssqpart ----
#pragma unroll
    for (int r = 0; r < 4; ++r) {
        int k = kt * 16 + (l4 << 2) + r;
        float S = 0.f;
#pragma unroll
        for (int pt = 0; pt < 8; ++pt) S += Spart[(pt * NN + nb) * KK + k];
        int cg = c0 + ctb * 16 + l15;
        const float* cp = cent + (size_t)k * CC + cg;
        float v0 = fmaf(-S, cp[0],  acc0[r]);
        float v1 = fmaf(-S, cp[16], acc1[r]);
        float* vp = vlad + ((size_t)nb * KK + k) * CC + cg;
        vp[0]  = v0;
        vp[16] = v1;
        float sq = fmaf(v0, v0, v1 * v1);
        sq += __shfl_xor(sq, 1);
        sq += __shfl_xor(sq, 2);
        sq += __shfl_xor(sq, 4);
        sq += __shfl_xor(sq, 8);
        if (l15 == 0) R2[(wv << 4) + (l4 << 2) + r] = sq;
    }
    __syncthreads();
    if (tid < 64) {
        int kt2 = tid >> 4, kl = tid & 15;
        ssqpart[(ct * NN + nb) * KK + tid] =
            R2[(kt2 << 4) + kl] + R2[((kt2 + 4) << 4) + kl];
    }
}

// ---------------- final scale: rinv/tinv from ssqpart, out = vlad*rinv*tinv ----------------
__global__ void k_final(const float* __restrict__ vlad, const float* __restrict__ ssqpart,
                        float* __restrict__ out) {
    size_t i4 = (size_t)blockIdx.x * 256 + threadIdx.x;
    int row = (int)(i4 >> 7);
    int n = row >> 6;
    int lane = threadIdx.x & 63;
    float s = 0.f;
#pragma unroll
    for (int ctile = 0; ctile < 8; ++ctile)
        s += ssqpart[(ctile * NN + n) * KK + lane];
    float iv = 1.0f / fmaxf(sqrtf(s), EPS);
    float rq = s * iv * iv;
#pragma unroll
    for (int off = 32; off > 0; off >>= 1) rq += __shfl_xor(rq, off);
    float tinv = 1.0f / fmaxf(sqrtf(rq), EPS);
    float rinv = __shfl(iv, row & 63);
    float4 v = ((const float4*)vlad)[i4];
    float sc = rinv * tinv;
    float4 o{v.x * sc, v.y * sc, v.z * sc, v.w * sc};
    ((float4*)out)[i4] = o;
}

extern "C" void kernel_launch(void* const* d_in, const int* in_sizes, int n_in,
                              void* d_out, int out_size, void* d_ws, size_t ws_size,
                              hipStream_t stream) {
    const float* x    = (const float*)d_in[0];
    const float* w    = (const float*)d_in[1];
    const float* bias = (const float*)d_in[2];
    const float* cent = (const float*)d_in[3];
    float* ws = (float*)d_ws;

    float* vlad    = ws;                              // 1048576
    float* Spart   = vlad + (size_t)NN * KK * CC;     // 16384
    float* ssqpart = Spart + 8 * NN * KK;             // 16384
    unsigned int* sab = (unsigned int*)(ssqpart + 8 * NN * KK);   // 1048576 u32

    float* out = (float*)d_out;

    k_logits<<<dim3(256), dim3(512), 0, stream>>>(x, w, bias, sab, Spart);
    k_vlad<<<dim3(256), dim3(512), 0, stream>>>(x, sab, Spart, cent, vlad, ssqpart);
    k_final<<<dim3(1024), dim3(256), 0, stream>>>(vlad, ssqpart, out);
}